// Round 2
// baseline (275.402 us; speedup 1.0000x reference)
//
#include <hip/hip_runtime.h>

// Patch_Embed_Center_Rotate: x (256,3,224,224) f32, P=16, grid 14x14.
// out = x everywhere, except patches with grid col j in [5,9] AND grid row
// k in [5,9], which are transposed within the 16x16 patch:
//   out[b,c, k*16+a3, j*16+a4] = x[b,c, k*16+a4, j*16+a3]
//
// v3: one block per (b,c) channel image (768 blocks x 512 threads).
//  - 768 = 256 CUs x 3 blocks, all co-resident (24 waves/CU, 26.9 KB LDS/blk
//    x3 = 81 KB of 160), every block does IDENTICAL work on a contiguous
//    196 KB range -> zero load imbalance, no small-block overhead.
//  - identity rows 0..79 and 160..223 are flat contiguous float4 ranges
//    (no div/mod at all); rows 80..159 copy the 36 non-center cols.
//  - center 80x80 region staged through LDS transposed-per-patch.
//    LDS row stride 84 floats (16B multiple) -> emit side reads are
//    16B-aligned ds_read_b128; scatter side spreads banks (step 84 mod 32).
//  - center load+scatter issued FIRST so LDS latency overlaps the
//    streaming copy phases; single __syncthreads before emit.
// Prior evidence (round 1 rocprof): kernel itself ~70-77 us (absent from
// top-5; harness fills at 92-95 us dominate the timed graph). Copy floor
// ~47 us at 6.3 TB/s.

#define W4 56          // float4 cols per 224-wide row
#define IMG_F4 12544   // 224 * 56 float4 per channel image
#define LDS_S 84       // LDS row stride in floats (16B multiple, spreads banks)
#define NT 512

__global__ __launch_bounds__(NT) void patch_rotate_kernel(
    const float4* __restrict__ x, float4* __restrict__ out) {
  const int bc = blockIdx.x;  // 0..767 fused (b,c)
  const float4* __restrict__ xs = x + (size_t)bc * IMG_F4;
  float4* __restrict__ os = out + (size_t)bc * IMG_F4;
  const int tid = threadIdx.x;

  __shared__ float ldsT[5 * 16 * LDS_S];  // 26880 B, out-ordered center region

  // ---- phase B-load: center region rows 80..159, f4 cols 20..39.
  // Load coalesced float4, scatter into LDS transposed within each 16x16
  // patch: LDS[row = ks*16 + a3][col = jl*16 + a4] with a3 = src col-in-patch,
  // a4 = src row-in-patch.
  for (int i = tid; i < 1600; i += NT) {
    const int sr = i / 20;   // 0..79: source row within center region (a4 part)
    const int c4 = i % 20;   // f4 col within center region
    const float4 v = xs[(80 + sr) * W4 + 20 + c4];
    const int ks = sr >> 4;            // strip 0..4
    const int ar = sr & 15;            // row within patch (= out a4)
    const int jl = c4 >> 2;            // local patch col 0..4
    const int ac0 = (c4 & 3) << 2;     // first src col within patch (= out a3)
    float* p = ldsT + (ks * 16 + ac0) * LDS_S + jl * 16 + ar;
    p[0 * LDS_S] = v.x;
    p[1 * LDS_S] = v.y;
    p[2 * LDS_S] = v.z;
    p[3 * LDS_S] = v.w;
  }

  // ---- phase A: identity copy (overlaps the LDS scatter latency).
  // rows 0..79: flat contiguous [0, 4480)
  for (int i = tid; i < 4480; i += NT) os[i] = xs[i];
  // rows 160..223: flat contiguous [8960, 12544)
  for (int i = 8960 + tid; i < IMG_F4; i += NT) os[i] = xs[i];
  // rows 80..159, non-center f4 cols {0..19, 40..55}
  for (int i = tid; i < 2880; i += NT) {
    const int r = i / 36;
    const int cc = i % 36;
    const int c4 = cc < 20 ? cc : cc + 20;
    const int idx = (80 + r) * W4 + c4;
    os[idx] = xs[idx];
  }

  __syncthreads();

  // ---- phase B-emit: coalesced float4 stores of the transposed center.
  // LDS reads are 16B-aligned (LDS_S and c4*4 both multiples of 4 floats).
  for (int i = tid; i < 1600; i += NT) {
    const int orr = i / 20;  // 0..79 = ks*16 + a3
    const int c4 = i % 20;
    const float* p = ldsT + orr * LDS_S + c4 * 4;
    float4 v;
    v.x = p[0]; v.y = p[1]; v.z = p[2]; v.w = p[3];
    os[(80 + orr) * W4 + 20 + c4] = v;
  }
}

extern "C" void kernel_launch(void* const* d_in, const int* in_sizes, int n_in,
                              void* d_out, int out_size, void* d_ws, size_t ws_size,
                              hipStream_t stream) {
  const float* x = (const float*)d_in[0];
  float* out = (float*)d_out;
  patch_rotate_kernel<<<768, NT, 0, stream>>>((const float4*)x, (float4*)out);
}

// Round 4
// 257.236 us; speedup vs baseline: 1.0706x; 1.0706x over previous
//
#include <hip/hip_runtime.h>

// Patch_Embed_Center_Rotate: x (256,3,224,224) f32, P=16, grid 14x14.
// out = x everywhere, except patches with grid col j in [5,9] AND grid row
// k in [5,9], which are transposed within the 16x16 patch:
//   out[b,c, k*16+a3, j*16+a4] = x[b,c, k*16+a4, j*16+a3]
//
// v4.1 = v1 (best measured structure: one thread per float4, 256-thr blocks,
// max occupancy -> max outstanding loads) + NONTEMPORAL hints on the
// identity stream (87% of traffic, zero reuse). Round-2 evidence: center
// path implementation is irrelevant (v1 scalar-gather == v2 LDS within
// noise); bulk stream runs ~4.3 TB/s vs 6.3 TB/s copy ceiling; theory is
// L2 write-allocate/read-allocate thrash on streaming data. Center keeps
// normal caching: its scattered 4B gathers depend on L2 line merging.
// (v4 compile fix: nontemporal builtins need a native vector type, not
// HIP_vector_type<float,4> -> use ext_vector_type(4) float.)

#define HH 224
#define WW 224
#define W4 56  // 224/4

typedef float vf4 __attribute__((ext_vector_type(4)));

__global__ __launch_bounds__(256) void patch_rotate_kernel(
    const float* __restrict__ x, float* __restrict__ out, int n4) {
  int idx = blockIdx.x * blockDim.x + threadIdx.x;  // float4 index into out
  if (idx >= n4) return;

  int bc   = idx / (HH * W4);   // fused (b,c)
  int rem  = idx % (HH * W4);
  int row  = rem / W4;          // 0..223
  int col4 = rem % W4;          // 0..55

  int k = row >> 4;     // grid row
  int j = col4 >> 2;    // grid col  (col4*4/16)

  bool center = (j >= 5) & (j <= 9) & (k >= 5) & (k <= 9);

  if (!center) {
    // identity, fully coalesced, streaming: bypass L2 allocation both ways
    vf4 v = __builtin_nontemporal_load((const vf4*)x + idx);
    __builtin_nontemporal_store(v, (vf4*)out + idx);
  } else {
    // transposed patch: out col a4 -> src row k*16+a4; out row a3 -> src col.
    // Scattered 4B loads; keep cached so L2 merges the 16 lanes sharing
    // each 64B source line.
    int a3  = row & 15;
    int a4b = (col4 & 3) << 2;            // first of 4 a4 values
    int base = (bc * HH + (k << 4)) * WW + (j << 4) + a3;  // a4 = 0 element
    vf4 v;
    v.x = x[base + (a4b + 0) * WW];
    v.y = x[base + (a4b + 1) * WW];
    v.z = x[base + (a4b + 2) * WW];
    v.w = x[base + (a4b + 3) * WW];
    *((vf4*)out + idx) = v;
  }
}

extern "C" void kernel_launch(void* const* d_in, const int* in_sizes, int n_in,
                              void* d_out, int out_size, void* d_ws, size_t ws_size,
                              hipStream_t stream) {
  const float* x = (const float*)d_in[0];
  float* out = (float*)d_out;
  int n4 = out_size / 4;                       // 9,633,792 float4s
  int threads = 256;
  int blocks = (n4 + threads - 1) / threads;   // 37,632
  patch_rotate_kernel<<<blocks, threads, 0, stream>>>(x, out, n4);
}

// Round 5
// 251.831 us; speedup vs baseline: 1.0936x; 1.0215x over previous
//
#include <hip/hip_runtime.h>

// Patch_Embed_Center_Rotate: x (256,3,224,224) f32, P=16, grid 14x14.
// out = x everywhere, except patches with grid col j in [5,9] AND grid row
// k in [5,9], which are transposed within the 16x16 patch:
//   out[b,c, k*16+a3, j*16+a4] = x[b,c, k*16+a4, j*16+a3]
//
// v5: block-role specialization, all-nontemporal.
//  - blocks [0, 37632): identity copy, one thread per float4 (v1 indexing,
//    proven fastest structure). Center lanes are PREDICATED OFF (no else
//    path) -> no wave executes two serialized paths (v4.1's rows-80..159
//    waves ran copy THEN gather back-to-back).
//  - blocks [37632, 42432): center patches. One 64-lane wave per 16x16
//    patch, 4 patches per 256-thr block. Coalesced f4 nt-load -> LDS
//    transpose (row stride 20 floats: scatter is exactly 2-way = free,
//    emit is 16B-aligned ds_read_b128, near-conflict-free) -> coalesced
//    f4 nt-store of full 64B lines.
//  - every global access is nontemporal and full-line: zero L2 allocation
//    on a zero-reuse 294 MB stream (nt gained ~16 us in round 4).
// Round-4 fill-normalized kernel ~60 us; copy floor ~47 us @ 6.29 TB/s.

#define W4 56          // float4 cols per 224-wide row
#define IMG_F4 12544   // 224*56 float4 per (b,c) image
#define NIDENT_BLKS 37632  // 768*12544/256

typedef float vf4 __attribute__((ext_vector_type(4)));

__global__ __launch_bounds__(256) void patch_rotate_kernel(
    const float* __restrict__ x, float* __restrict__ out) {
  const int tid = threadIdx.x;

  if (blockIdx.x < NIDENT_BLKS) {
    // ---- identity role: contiguous f4 copy, center lanes masked off.
    const int idx = blockIdx.x * 256 + tid;   // f4 index, < 9,633,792
    const int rem = idx % IMG_F4;
    const int row = rem / W4;                 // 0..223
    const int col4 = rem % W4;                // 0..55
    const int k = row >> 4;
    const int j = col4 >> 2;
    const bool center = (j >= 5) & (j <= 9) & (k >= 5) & (k <= 9);
    if (!center) {
      vf4 v = __builtin_nontemporal_load((const vf4*)x + idx);
      __builtin_nontemporal_store(v, (vf4*)out + idx);
    }
    return;
  }

  // ---- center role: one wave per patch, LDS in-patch transpose.
  __shared__ float ldsT[4][16][20];           // [patch][out-row][out-col], 5120B
  const int pb = blockIdx.x - NIDENT_BLKS;    // 0..4799
  const int lp = tid >> 6;                    // local patch 0..3
  const int l  = tid & 63;                    // lane
  const int p  = pb * 4 + lp;                 // global center patch 0..19199
  const int q  = p / 25;                      // (b,c) image 0..767
  const int pi = p % 25;
  const int kk = 5 + pi / 5;                  // grid row 5..9
  const int jj = 5 + pi % 5;                  // grid col 5..9
  const float* __restrict__ xs = x + (size_t)q * (IMG_F4 * 4);
  float* __restrict__ os = out + (size_t)q * (IMG_F4 * 4);

  const int r  = l >> 2;                      // row within patch 0..15
  const int c0 = (l & 3) << 2;                // first col within patch {0,4,8,12}

  // load f4 at patch (row r, cols c0..c0+3): fully coalesced per wave.
  const vf4 v = __builtin_nontemporal_load(
      (const vf4*)(xs + (kk * 16 + r) * 224 + jj * 16 + c0));
  // scatter transposed: ldsT[out-row = src col][out-col = src row].
  // banks: (sc*20 + r) mod 32 -> each bank hit by exactly 2 lanes (free).
  ldsT[lp][c0 + 0][r] = v.x;
  ldsT[lp][c0 + 1][r] = v.y;
  ldsT[lp][c0 + 2][r] = v.z;
  ldsT[lp][c0 + 3][r] = v.w;

  __syncthreads();

  // emit: 16B-aligned contiguous LDS read, coalesced full-line nt store.
  vf4 w;
  w.x = ldsT[lp][r][c0 + 0];
  w.y = ldsT[lp][r][c0 + 1];
  w.z = ldsT[lp][r][c0 + 2];
  w.w = ldsT[lp][r][c0 + 3];
  __builtin_nontemporal_store(
      w, (vf4*)(os + (kk * 16 + r) * 224 + jj * 16 + c0));
}

extern "C" void kernel_launch(void* const* d_in, const int* in_sizes, int n_in,
                              void* d_out, int out_size, void* d_ws, size_t ws_size,
                              hipStream_t stream) {
  const float* x = (const float*)d_in[0];
  float* out = (float*)d_out;
  const int blocks = NIDENT_BLKS + 4800;  // identity + center roles
  patch_rotate_kernel<<<blocks, 256, 0, stream>>>(x, out);
}